// Round 7
// baseline (131.639 us; speedup 1.0000x reference)
//
#include <hip/hip_runtime.h>
#include <stdint.h>

// ModulatedConv2D: B=8, IC=OC=512, K=3, H=W=32
// 4 dispatches: style (sm, sm2), wts (Wtf repack + dpart), xsp (x repack),
// conv (implicit GEMM, 32x32x16 f16 MFMA).
//
// R7 change: conv is pinned at 47us / MfmaUtil 33% across SIX structurally
// different versions (reg-dbuf x2, LDS-A, 2x occupancy, counted-vmcnt,
// 2x-reuse tiles) -- every per-CU resource model fails. Before touching
// conv again: measure the unmeasured ~83us. prep split into wts_kernel +
// xsp_kernel (separate rocprof rows next round), and xsp parallelism 4x'd
// (256 -> 1024 blocks, one per (b,h,ic-quarter); LDS 33KB -> 8.7KB;
// identical index math). conv kept exactly at R6 (best total, 127.9us).

#define B_   8
#define IC_  512
#define OC_  512

static constexpr float RC_DENSE = 0.04419417382415922f;   // 1/sqrt(512)
static constexpr float RC_CONV  = 0.014731391274719739f;  // 1/sqrt(4608)

typedef _Float16 half8    __attribute__((ext_vector_type(8)));
typedef float    floatx16 __attribute__((ext_vector_type(16)));

// async global->LDS, 16B per lane; LDS dest = wave-uniform base + lane*16
__device__ __forceinline__ void g2l(const void* g, void* l) {
  __builtin_amdgcn_global_load_lds(
      (const __attribute__((address_space(1))) void*)g,
      (__attribute__((address_space(3))) void*)l, 16, 0, 0);
}

// ---- sm = (w@(RC_DENSE*dw) + db + 1)*RC_CONV ; sm2 = sm^2 ----
__global__ __launch_bounds__(256) void style_kernel(
    const float* __restrict__ wv, const float* __restrict__ dw,
    const float* __restrict__ db, float* __restrict__ sm,
    float* __restrict__ sm2) {
  const int b = blockIdx.y;
  const int i = blockIdx.x * 64 + (threadIdx.x & 63);
  const int jg = threadIdx.x >> 6;
  __shared__ float red[4][64];
  float p = 0.f;
  for (int j = jg * 128; j < jg * 128 + 128; ++j)
    p += wv[b * IC_ + j] * dw[(size_t)j * IC_ + i];
  red[jg][threadIdx.x & 63] = p;
  __syncthreads();
  if (threadIdx.x < 64) {
    float s = red[0][threadIdx.x] + red[1][threadIdx.x] +
              red[2][threadIdx.x] + red[3][threadIdx.x];
    s = s * RC_DENSE + db[i] + 1.0f;
    float v = s * RC_CONV;
    sm[b * IC_ + i] = v;
    sm2[b * IC_ + i] = v * v;
  }
}

// ---------------- wts: 256 blocks ----------------
// per (by2=bid>>4, icb): 32oc x 32ic half-tile; Wtf[by][icb][m 36][oc64][8]
// + dpart[icb][b][oc] = sum_icl sm2 * sum_t cw^2 (disjoint oc, no atomics)
__global__ __launch_bounds__(256) void wts_kernel(
    const float* __restrict__ cw, const float* __restrict__ sm2,
    _Float16* __restrict__ Wtf, float* __restrict__ dpart) {
  __shared__ __align__(16) char smem[26624];
  _Float16* LA = (_Float16*)smem;                // 18432 B
  float* redall = (float*)(smem + 18432);        // 8192 B (8b x 8g x 32oc)
  const int bid = blockIdx.x;
  const int tid = threadIdx.x;
  const int by2 = bid >> 4, icb = bid & 15;
  const int by = by2 >> 1, h2 = by2 & 1;
  const int oc0 = by * 64 + h2 * 32, ic0 = icb * 32;
  const int ocl = tid & 31, g = tid >> 5;        // g 0..7
  float sq4[4] = {};
  for (int m = 0; m < 36; ++m) {
    int r = m * 8 + g;                 // r = t*32+icl; t=m>>2, icl=8*(m&3)+g
    int t = r >> 5, icl = r & 31;
    float v = cw[(size_t)(t * IC_ + ic0 + icl) * OC_ + oc0 + ocl];  // 128B seg
    sq4[m & 3] += v * v;
    LA[m * 256 + ocl * 8 + g] = (_Float16)v;     // ktq == m, j == g
  }
  for (int b = 0; b < 8; ++b) {
    float p = 0.f;
    for (int s = 0; s < 4; ++s)
      p += sm2[b * IC_ + ic0 + g + 8 * s] * sq4[s];
    redall[(b * 8 + g) * 32 + ocl] = p;
  }
  __syncthreads();
  // Wtf: 1152 contiguous-per-wave b128 chunks
  _Float16* dst = Wtf + (size_t)(by * 16 + icb) * 18432;
  for (int it = 0; it < 5; ++it) {
    int c = it * 256 + tid;
    if (c < 1152) {
      int m = c >> 5, o2 = c & 31;
      *(half8*)(dst + (size_t)(m * 64 + h2 * 32 + o2) * 8) =
          *(const half8*)&LA[m * 256 + o2 * 8];
    }
  }
  // dpart: reduce over g
  const int bb = tid >> 5, o3 = tid & 31;
  float s = 0.f;
  for (int g2 = 0; g2 < 8; ++g2) s += redall[(bb * 8 + g2) * 32 + o3];
  dpart[(size_t)icb * 4096 + bb * OC_ + oc0 + o3] = s;
}

// ---------------- xsp: 1024 blocks (h 32, b 8, q 4) ----------------
// per (b,h,q): ic quarter [q*128, q*128+128) = icbs [q*4, q*4+4).
// Phase 1: x row -> LDS transpose (w-major), modulated by sm, f16.
// Phase 2: xsp[b][icb][r34][kk2][kq2][C34][8] f16 with halo cols + 0-rows.
__global__ __launch_bounds__(256) void xsp_kernel(
    const float* __restrict__ x, const float* __restrict__ sm,
    _Float16* __restrict__ xsp) {
  __shared__ __align__(16) _Float16 Xt[32][136];   // [w][ic_local], 8704 B
  const int h = blockIdx.x, b = blockIdx.y, q = blockIdx.z;
  const int tid = threadIdx.x;
  const int ic0 = q * 128;
  for (int k = 0; k < 4; ++k) {
    int idx = k * 256 + tid;             // 128 ic * 8 w-quads
    int icl = idx >> 3, wc = (idx & 7) * 4;
    float4 v = *(const float4*)&x[((size_t)(b * IC_ + ic0 + icl) * 32 + h) * 32 + wc];
    float s = sm[b * IC_ + ic0 + icl];
    Xt[wc + 0][icl] = (_Float16)(v.x * s);
    Xt[wc + 1][icl] = (_Float16)(v.y * s);
    Xt[wc + 2][icl] = (_Float16)(v.z * s);
    Xt[wc + 3][icl] = (_Float16)(v.w * s);
  }
  __syncthreads();
  _Float16* xb = xsp + (size_t)b * 16 * 36992;
  const int r = h + 1;
  half8 z = {};
  for (int it = 0; it < 3; ++it) {       // 4 icb * 4 kkq * 34 C = 544 chunks
    int c = it * 256 + tid;
    if (c < 544) {
      int icbl = c / 136, rem = c - 136 * icbl, kkq = rem / 34, C = rem - 34 * kkq;
      half8 val = z;
      if (C != 0 && C != 33)
        val = *(const half8*)&Xt[C - 1][icbl * 32 + kkq * 8];
      int icb = q * 4 + icbl;
      *(half8*)&xb[(size_t)icb * 36992 + (size_t)r * 1088 + kkq * 272 + C * 8] = val;
    }
  }
  if (h == 0 || h == 31) {               // zero top/bottom padded rows
    const int rz = (h == 0) ? 0 : 33;
    for (int it = 0; it < 3; ++it) {
      int c = it * 256 + tid;
      if (c < 544) {
        int icbl = c / 136, rem = c - 136 * icbl, kkq = rem / 34, C = rem - 34 * kkq;
        int icb = q * 4 + icbl;
        *(half8*)&xb[(size_t)icb * 36992 + (size_t)rz * 1088 + kkq * 272 + C * 8] = z;
      }
    }
  }
}

// ---- conv: block 32oc x 256px (8 rows), grid (x 16, bx 4, b 8) = 512 ----
// blockIdx.x = byq + 8*hoc; XCD = linear%8 = byq (weight slice locality).
// 4 waves/block, wave w owns output rows h0+2w, h0+2w+1 (two 32x32 tiles,
// acc[2]x16): 18 MFMA per sub-step from 9 A + 12 X ds_reads (s/kh reuse).
// 32 sub-steps (icb x kk); per stage A-quarter (9216 B) + X 10 rows
// (10880 B) via global_load_lds, double-buffered (LDS ~41.4 KB, 2 bl/CU).
// Staging = 20 wave-uniform 64-chunk groups, exactly 5 PER WAVE:
// w0 A0-4, w1 A5-8+X0, w2 X1-5, w3 X6-10(last 40 lanes) -> vmcnt(5).
__global__ __launch_bounds__(256, 2) void conv_kernel(
    const _Float16* __restrict__ Wtf,   // [8 byq][16 icb][36 m][64 oc][8]
    const _Float16* __restrict__ xsp,   // [8 b][16 icb][34 r][2 kk][2 kq][34 C][8]
    const float* __restrict__ dpart,    // [16 icb][8 b][512 oc]
    float* __restrict__ out) {          // [8][512][32][32]
  const int byq = blockIdx.x & 7, hoc = blockIdx.x >> 3;
  const int bx = blockIdx.y, b = blockIdx.z;
  const int tid = threadIdx.x, lane = tid & 63, w = tid >> 6;
  const int n = lane & 31, kq = lane >> 5;
  const int h0 = bx * 8;                // output rows h0..h0+7; padded h0..h0+9

  __shared__ __align__(16) _Float16 As[2][4608];   //  9216 B each (18r x 256)
  __shared__ __align__(16) _Float16 Xs[2][5440];   // 10880 B each (10r x 544)
  __shared__ float redd[8][32];
  __shared__ float dvl[32];

  const _Float16* gX = xsp + (size_t)b * 16 * 36992 + (size_t)h0 * 1088;
  const _Float16* gA = Wtf + (size_t)byq * 16 * 18432 + hoc * 256;

  // A chunks c in [0,576): r=c>>5 (0..17), o2=c&31;
  //   src halfs = icb*18432 + ((r>>1)*4 + kk*2 + (r&1))*512 + hoc*256 + o2*8
  // X chunks c in [0,680): r=c/68 (0..9), o=c%68;
  //   src halfs = icb*36992 + kk*544 + r*1088 + o*8
  auto stage = [&](int st, int p) {
    const int icb = st >> 1, kk = st & 1;
    const _Float16* a = gA + (size_t)icb * 18432 + kk * 1024;
    const _Float16* xg = gX + (size_t)icb * 36992 + kk * 544;
    if (w == 0) {
#pragma unroll
      for (int k = 0; k < 5; ++k) {      // A groups 0-4
        int c = k * 64 + lane;
        int r = c >> 5, o2 = c & 31;
        g2l(a + ((r >> 1) * 4 + (r & 1)) * 512 + o2 * 8, &As[p][c * 8]);
      }
    } else if (w == 1) {
#pragma unroll
      for (int k = 0; k < 4; ++k) {      // A groups 5-8
        int c = (5 + k) * 64 + lane;
        int r = c >> 5, o2 = c & 31;
        g2l(a + ((r >> 1) * 4 + (r & 1)) * 512 + o2 * 8, &As[p][c * 8]);
      }
      {                                  // X group 0
        int c = lane, r = c / 68, o = c - r * 68;
        g2l(xg + r * 1088 + o * 8, &Xs[p][c * 8]);
      }
    } else if (w == 2) {
#pragma unroll
      for (int k = 0; k < 5; ++k) {      // X groups 1-5
        int c = (1 + k) * 64 + lane;
        int r = c / 68, o = c - r * 68;
        g2l(xg + r * 1088 + o * 8, &Xs[p][c * 8]);
      }
    } else {
#pragma unroll
      for (int k = 0; k < 4; ++k) {      // X groups 6-9
        int c = (6 + k) * 64 + lane;
        int r = c / 68, o = c - r * 68;
        g2l(xg + r * 1088 + o * 8, &Xs[p][c * 8]);
      }
      {                                  // X group 10 (partial: 40 lanes)
        int c = 640 + lane;
        if (lane < 40) {
          int r = c / 68, o = c - r * 68;
          g2l(xg + r * 1088 + o * 8, &Xs[p][c * 8]);
        }
      }
    }
  };

  floatx16 acc[2] = {};
  stage(0, 0);                           // prologue: 5 g2l in flight
  for (int st = 0; st < 32; ++st) {
    const int cur = st & 1;
    if (st + 1 < 32) {
      stage(st + 1, cur ^ 1);            // issue next (5 g2l) -> 10 in flight
      asm volatile("s_waitcnt vmcnt(5)" ::: "memory");  // my buf[cur] done
    } else {
      asm volatile("s_waitcnt vmcnt(0)" ::: "memory");
    }
    __builtin_amdgcn_s_barrier();        // all waves' buf[cur] writes done
    __builtin_amdgcn_sched_barrier(0);   // pin: no ds_read hoists above
    const _Float16* Ap = &As[cur][0] + kq * 256 + n * 8;
    const _Float16* Xp = &Xs[cur][0] + (2 * w) * 544 + kq * 272 + n * 8;
    half8 a[9];
#pragma unroll
    for (int t = 0; t < 9; ++t) a[t] = *(const half8*)(Ap + t * 512);
    __builtin_amdgcn_s_setprio(1);
#pragma unroll
    for (int s = 0; s < 4; ++s) {        // staged row 2w+s; out rows j=0,1
#pragma unroll
      for (int kw = 0; kw < 3; ++kw) {
        half8 xv = *(const half8*)(Xp + s * 544 + kw * 8);
#pragma unroll
        for (int kh = 0; kh < 3; ++kh) {
          int j = s - kh;
          if (j >= 0 && j < 2)
            acc[j] = __builtin_amdgcn_mfma_f32_32x32x16_f16(
                a[kh * 3 + kw], xv, acc[j], 0, 0, 0);
        }
      }
    }
    __builtin_amdgcn_s_setprio(0);
    __builtin_amdgcn_sched_barrier(0);   // pin: no ds_read sinks below
    __builtin_amdgcn_s_barrier();        // buf[cur^1] reads done (WAR)
  }

  // epilogue: reduce dpart over 16 icb -> dvl[32], then plain stores
  const int oc0 = byq * 64 + hoc * 32;
  __syncthreads();
  {
    const int oc_l = tid & 31, ig = tid >> 5;
    float s = dpart[(size_t)(ig * 2) * 4096 + b * OC_ + oc0 + oc_l] +
              dpart[(size_t)(ig * 2 + 1) * 4096 + b * OC_ + oc0 + oc_l];
    redd[ig][oc_l] = s;
  }
  __syncthreads();
  if (tid < 32) {
    float s = 1e-8f;
#pragma unroll
    for (int g = 0; g < 8; ++g) s += redd[g][tid];
    dvl[tid] = rsqrtf(s);
  }
  __syncthreads();
  // D col(px)=n, row(oc within 32)=(rg&3)+8*(rg>>2)+4*kq
  const int r0 = h0 + 2 * w;
#pragma unroll
  for (int rg = 0; rg < 16; ++rg) {
    const int row = (rg & 3) + 8 * (rg >> 2) + 4 * kq;
    const float dv = dvl[row];
    float* op = out + ((size_t)b * OC_ + oc0 + row) * 1024 + r0 * 32 + n;
    op[0]  = acc[0][rg] * dv;
    op[32] = acc[1][rg] * dv;
  }
}

extern "C" void kernel_launch(void* const* d_in, const int* in_sizes, int n_in,
                              void* d_out, int out_size, void* d_ws, size_t ws_size,
                              hipStream_t stream) {
  const float* x       = (const float*)d_in[0];
  const float* w       = (const float*)d_in[1];
  const float* conv_w  = (const float*)d_in[2];
  const float* dense_w = (const float*)d_in[3];
  const float* dense_b = (const float*)d_in[4];
  float* out = (float*)d_out;

  char* ws = (char*)d_ws;
  float*    sm    = (float*)ws;                        // 16 KB
  float*    sm2   = (float*)(ws + (16 << 10));         // 16 KB
  float*    dpart = (float*)(ws + (32 << 10));         // 256 KB
  _Float16* Wtf   = (_Float16*)(ws + (288 << 10));               // 4,718,592 B
  _Float16* xsp   = (_Float16*)(ws + (288 << 10) + 4718592);     // 9,469,952 B

  style_kernel<<<dim3(8, B_), 256, 0, stream>>>(w, dense_w, dense_b, sm, sm2);
  wts_kernel<<<256, 256, 0, stream>>>(conv_w, sm2, Wtf, dpart);
  xsp_kernel<<<dim3(32, B_, 4), 256, 0, stream>>>(x, sm, xsp);
  conv_kernel<<<dim3(16, 4, B_), 256, 0, stream>>>(Wtf, xsp, dpart, out);
}

// Round 8
// 129.159 us; speedup vs baseline: 1.0192x; 1.0192x over previous
//
#include <hip/hip_runtime.h>
#include <stdint.h>

// ModulatedConv2D: B=8, IC=OC=512, K=3, H=W=32
// 3 dispatches: style (sm, sm2), prep (Wtf repack + dpart demod partials +
// xsp repack), conv (implicit GEMM, 32x32x16 f16 MFMA).
//
// R8 change: conv step-time is CONSTANT ~3500cyc across 7 variants with
// wildly different bandwidth demands -> latency chain, not throughput.
// Shared property of all 7: prefetch depth 1 (stage slack ~2300cyc <
// g2l completion latency under load ~2500-3500cyc) -> every version
// stalls at its wait identically. Fix: depth-2 prefetch, triple-buffered
// LDS (60KB, still 2 blocks/CU), vmcnt(10) (5 g2l/wave/stage, 2 stages
// in flight). prep/style reverted to R6's fused best (127.9us total).

#define B_   8
#define IC_  512
#define OC_  512

static constexpr float RC_DENSE = 0.04419417382415922f;   // 1/sqrt(512)
static constexpr float RC_CONV  = 0.014731391274719739f;  // 1/sqrt(4608)

typedef _Float16 half8    __attribute__((ext_vector_type(8)));
typedef float    floatx16 __attribute__((ext_vector_type(16)));

// async global->LDS, 16B per lane; LDS dest = wave-uniform base + lane*16
__device__ __forceinline__ void g2l(const void* g, void* l) {
  __builtin_amdgcn_global_load_lds(
      (const __attribute__((address_space(1))) void*)g,
      (__attribute__((address_space(3))) void*)l, 16, 0, 0);
}

// ---- sm = (w@(RC_DENSE*dw) + db + 1)*RC_CONV ; sm2 = sm^2 ----
__global__ __launch_bounds__(256) void style_kernel(
    const float* __restrict__ wv, const float* __restrict__ dw,
    const float* __restrict__ db, float* __restrict__ sm,
    float* __restrict__ sm2) {
  const int b = blockIdx.y;
  const int i = blockIdx.x * 64 + (threadIdx.x & 63);
  const int jg = threadIdx.x >> 6;
  __shared__ float red[4][64];
  float p = 0.f;
  for (int j = jg * 128; j < jg * 128 + 128; ++j)
    p += wv[b * IC_ + j] * dw[(size_t)j * IC_ + i];
  red[jg][threadIdx.x & 63] = p;
  __syncthreads();
  if (threadIdx.x < 64) {
    float s = red[0][threadIdx.x] + red[1][threadIdx.x] +
              red[2][threadIdx.x] + red[3][threadIdx.x];
    s = s * RC_DENSE + db[i] + 1.0f;
    float v = s * RC_CONV;
    sm[b * IC_ + i] = v;
    sm2[b * IC_ + i] = v * v;
  }
}

// ---------------- prep: 512 blocks (2/CU) ----------------
// bid<256 (wts role): 32oc x 32ic half-tile; Wtf[by][icb][ktq 36][oc64][8] f16
//   + dpart[icb][b][oc] = sum_icl sm2 * sum_t cw^2 (disjoint oc, no atomics)
// bid>=256 (xsp role): per (b,h) row; xsp[b][icb][r34][kk2][kq2][C34][8] f16
__global__ __launch_bounds__(256) void prep_kernel(
    const float* __restrict__ cw, const float* __restrict__ x,
    const float* __restrict__ sm, const float* __restrict__ sm2,
    _Float16* __restrict__ Wtf, float* __restrict__ dpart,
    _Float16* __restrict__ xsp) {
  __shared__ __align__(16) char smem[33280];
  const int bid = blockIdx.x;
  const int tid = threadIdx.x;
  if (bid < 256) {
    // ---------------- wts + dpart role ----------------
    _Float16* LA = (_Float16*)smem;                // 18432 B
    float* redall = (float*)(smem + 18432);        // 8192 B (8b x 8g x 32oc)
    const int by2 = bid >> 4, icb = bid & 15;
    const int by = by2 >> 1, h2 = by2 & 1;
    const int oc0 = by * 64 + h2 * 32, ic0 = icb * 32;
    const int ocl = tid & 31, g = tid >> 5;        // g 0..7
    float sq4[4] = {};
    for (int m = 0; m < 36; ++m) {
      int r = m * 8 + g;                 // r = t*32+icl; t=m>>2, icl=8*(m&3)+g
      int t = r >> 5, icl = r & 31;
      float v = cw[(size_t)(t * IC_ + ic0 + icl) * OC_ + oc0 + ocl];  // 128B seg
      sq4[m & 3] += v * v;
      LA[m * 256 + ocl * 8 + g] = (_Float16)v;     // ktq == m, j == g
    }
    for (int b = 0; b < 8; ++b) {
      float p = 0.f;
      for (int s = 0; s < 4; ++s)
        p += sm2[b * IC_ + ic0 + g + 8 * s] * sq4[s];
      redall[(b * 8 + g) * 32 + ocl] = p;
    }
    __syncthreads();
    // Wtf: 1152 contiguous-per-wave b128 chunks
    _Float16* dst = Wtf + (size_t)(by * 16 + icb) * 18432;
    for (int it = 0; it < 5; ++it) {
      int c = it * 256 + tid;
      if (c < 1152) {
        int m = c >> 5, o2 = c & 31;
        *(half8*)(dst + (size_t)(m * 64 + h2 * 32 + o2) * 8) =
            *(const half8*)&LA[m * 256 + o2 * 8];
      }
    }
    // dpart: reduce over g
    const int bb = tid >> 5, o3 = tid & 31;
    float s = 0.f;
    for (int g2 = 0; g2 < 8; ++g2) s += redall[(bb * 8 + g2) * 32 + o3];
    dpart[(size_t)icb * 4096 + bb * OC_ + oc0 + o3] = s;
  } else {
    // ---------------- xsp role ----------------
    _Float16* Xt = (_Float16*)smem;                // 32*520*2 = 33280 B
    const int rb = bid - 256;
    const int b = rb >> 5, h = rb & 31;
    for (int k = 0; k < 16; ++k) {
      int idx = k * 256 + tid;           // 512 ic * 8 w-quads
      int ic = idx >> 3, wc = (idx & 7) * 4;
      float4 v = *(const float4*)&x[((size_t)(b * IC_ + ic) * 32 + h) * 32 + wc];
      float s = sm[b * IC_ + ic];
      Xt[(wc + 0) * 520 + ic] = (_Float16)(v.x * s);
      Xt[(wc + 1) * 520 + ic] = (_Float16)(v.y * s);
      Xt[(wc + 2) * 520 + ic] = (_Float16)(v.z * s);
      Xt[(wc + 3) * 520 + ic] = (_Float16)(v.w * s);
    }
    __syncthreads();
    _Float16* xb = xsp + (size_t)b * 16 * 36992;
    const int r = h + 1;
    half8 z = {};
    for (int it = 0; it < 9; ++it) {     // 16 icb * 4 kkq * 34 C = 2176 chunks
      int c = it * 256 + tid;
      if (c < 2176) {
        int icb = c / 136, rem = c - 136 * icb, kkq = rem / 34, C = rem - 34 * kkq;
        half8 val = z;
        if (C != 0 && C != 33)
          val = *(const half8*)&Xt[(C - 1) * 520 + icb * 32 + kkq * 8];
        *(half8*)&xb[(size_t)icb * 36992 + (size_t)r * 1088 + kkq * 272 + C * 8] = val;
      }
    }
    if (h == 0 || h == 31) {             // zero top/bottom padded rows
      const int rz = (h == 0) ? 0 : 33;
      for (int it = 0; it < 9; ++it) {
        int c = it * 256 + tid;
        if (c < 2176) {
          int icb = c / 136, rem = c - 136 * icb, kkq = rem / 34, C = rem - 34 * kkq;
          *(half8*)&xb[(size_t)icb * 36992 + (size_t)rz * 1088 + kkq * 272 + C * 8] = z;
        }
      }
    }
  }
}

// ---- conv: block 32oc x 256px (8 rows), grid (x 16, bx 4, b 8) = 512 ----
// blockIdx.x = byq + 8*hoc; XCD = linear%8 = byq (weight slice locality).
// 4 waves/block, wave w owns output rows h0+2w, h0+2w+1 (two 32x32 tiles,
// acc[2]x16): 18 MFMA per sub-step from 9 A + 12 X ds_reads (s/kh reuse).
// 32 sub-steps (icb x kk); per stage A-quarter (9216 B) + X 10 rows
// (10880 B) via global_load_lds, TRIPLE-buffered (60 KB LDS, 2 blocks/CU).
// Depth-2 prefetch: stage(st+2) issued each step; vmcnt(10) waits only for
// stage(st) (5 g2l/wave/stage, 10 newer in flight across both barriers).
// Buffer rotation %3: stage(st+2) writes (st+2)%3 != st%3 being read;
// readers of (st+2)%3 finished at the previous trailing barrier (WAR ok).
__global__ __launch_bounds__(256, 2) void conv_kernel(
    const _Float16* __restrict__ Wtf,   // [8 byq][16 icb][36 m][64 oc][8]
    const _Float16* __restrict__ xsp,   // [8 b][16 icb][34 r][2 kk][2 kq][34 C][8]
    const float* __restrict__ dpart,    // [16 icb][8 b][512 oc]
    float* __restrict__ out) {          // [8][512][32][32]
  const int byq = blockIdx.x & 7, hoc = blockIdx.x >> 3;
  const int bx = blockIdx.y, b = blockIdx.z;
  const int tid = threadIdx.x, lane = tid & 63, w = tid >> 6;
  const int n = lane & 31, kq = lane >> 5;
  const int h0 = bx * 8;                // output rows h0..h0+7; padded h0..h0+9

  __shared__ __align__(16) _Float16 As[3][4608];   //  9216 B each (18r x 256)
  __shared__ __align__(16) _Float16 Xs[3][5440];   // 10880 B each (10r x 544)
  __shared__ float redd[8][32];
  __shared__ float dvl[32];

  const _Float16* gX = xsp + (size_t)b * 16 * 36992 + (size_t)h0 * 1088;
  const _Float16* gA = Wtf + (size_t)byq * 16 * 18432 + hoc * 256;

  // A chunks c in [0,576): r=c>>5 (0..17), o2=c&31;
  //   src halfs = icb*18432 + ((r>>1)*4 + kk*2 + (r&1))*512 + hoc*256 + o2*8
  // X chunks c in [0,680): r=c/68 (0..9), o=c%68
  //   src halfs = icb*36992 + kk*544 + r*1088 + o*8
  // 64-chunk groups; exactly 5 g2l PER WAVE:
  //   w0: A0-4; w1: A5-8 + X0; w2: X1-5; w3: X6-9 + X10(40 lanes)
  auto stage = [&](int st, int p) {
    const int icb = st >> 1, kk = st & 1;
    const _Float16* a = gA + (size_t)icb * 18432 + kk * 1024;
    const _Float16* xg = gX + (size_t)icb * 36992 + kk * 544;
    if (w == 0) {
#pragma unroll
      for (int k = 0; k < 5; ++k) {      // A groups 0-4
        int c = k * 64 + lane;
        int r = c >> 5, o2 = c & 31;
        g2l(a + ((r >> 1) * 4 + (r & 1)) * 512 + o2 * 8, &As[p][c * 8]);
      }
    } else if (w == 1) {
#pragma unroll
      for (int k = 0; k < 4; ++k) {      // A groups 5-8
        int c = (5 + k) * 64 + lane;
        int r = c >> 5, o2 = c & 31;
        g2l(a + ((r >> 1) * 4 + (r & 1)) * 512 + o2 * 8, &As[p][c * 8]);
      }
      {                                  // X group 0
        int c = lane, r = c / 68, o = c - r * 68;
        g2l(xg + r * 1088 + o * 8, &Xs[p][c * 8]);
      }
    } else if (w == 2) {
#pragma unroll
      for (int k = 0; k < 5; ++k) {      // X groups 1-5
        int c = (1 + k) * 64 + lane;
        int r = c / 68, o = c - r * 68;
        g2l(xg + r * 1088 + o * 8, &Xs[p][c * 8]);
      }
    } else {
#pragma unroll
      for (int k = 0; k < 4; ++k) {      // X groups 6-9
        int c = (6 + k) * 64 + lane;
        int r = c / 68, o = c - r * 68;
        g2l(xg + r * 1088 + o * 8, &Xs[p][c * 8]);
      }
      {                                  // X group 10 (partial: 40 lanes)
        int c = 640 + lane;
        if (lane < 40) {
          int r = c / 68, o = c - r * 68;
          g2l(xg + r * 1088 + o * 8, &Xs[p][c * 8]);
        }
      }
    }
  };

  floatx16 acc[2] = {};
  stage(0, 0);                           // depth-2 prologue: 10 g2l in flight
  stage(1, 1);
  int cur = 0;
  for (int st = 0; st < 32; ++st) {
    if (st + 2 < 32) {
      int p2 = cur + 2; if (p2 >= 3) p2 -= 3;
      stage(st + 2, p2);                 // issue next-next (5 g2l) -> 15
      asm volatile("s_waitcnt vmcnt(10)" ::: "memory");  // stage(st) done
    } else if (st == 30) {
      asm volatile("s_waitcnt vmcnt(5)" ::: "memory");
    } else {
      asm volatile("s_waitcnt vmcnt(0)" ::: "memory");
    }
    __builtin_amdgcn_s_barrier();        // all waves' buf[cur] writes done
    __builtin_amdgcn_sched_barrier(0);   // pin: no ds_read hoists above
    const _Float16* Ap = &As[cur][0] + kq * 256 + n * 8;
    const _Float16* Xp = &Xs[cur][0] + (2 * w) * 544 + kq * 272 + n * 8;
    half8 a[9];
#pragma unroll
    for (int t = 0; t < 9; ++t) a[t] = *(const half8*)(Ap + t * 512);
    __builtin_amdgcn_s_setprio(1);
#pragma unroll
    for (int s = 0; s < 4; ++s) {        // staged row 2w+s; out rows j=0,1
#pragma unroll
      for (int kw = 0; kw < 3; ++kw) {
        half8 xv = *(const half8*)(Xp + s * 544 + kw * 8);
#pragma unroll
        for (int kh = 0; kh < 3; ++kh) {
          int j = s - kh;
          if (j >= 0 && j < 2)
            acc[j] = __builtin_amdgcn_mfma_f32_32x32x16_f16(
                a[kh * 3 + kw], xv, acc[j], 0, 0, 0);
        }
      }
    }
    __builtin_amdgcn_s_setprio(0);
    __builtin_amdgcn_sched_barrier(0);   // pin: no ds_read sinks below
    __builtin_amdgcn_s_barrier();        // buf[cur] reads done (WAR for st+3)
    ++cur; if (cur >= 3) cur = 0;
  }

  // epilogue: reduce dpart over 16 icb -> dvl[32], then plain stores
  const int oc0 = byq * 64 + hoc * 32;
  __syncthreads();
  {
    const int oc_l = tid & 31, ig = tid >> 5;
    float s = dpart[(size_t)(ig * 2) * 4096 + b * OC_ + oc0 + oc_l] +
              dpart[(size_t)(ig * 2 + 1) * 4096 + b * OC_ + oc0 + oc_l];
    redd[ig][oc_l] = s;
  }
  __syncthreads();
  if (tid < 32) {
    float s = 1e-8f;
#pragma unroll
    for (int g = 0; g < 8; ++g) s += redd[g][tid];
    dvl[tid] = rsqrtf(s);
  }
  __syncthreads();
  // D col(px)=n, row(oc within 32)=(rg&3)+8*(rg>>2)+4*kq
  const int r0 = h0 + 2 * w;
#pragma unroll
  for (int rg = 0; rg < 16; ++rg) {
    const int row = (rg & 3) + 8 * (rg >> 2) + 4 * kq;
    const float dv = dvl[row];
    float* op = out + ((size_t)b * OC_ + oc0 + row) * 1024 + r0 * 32 + n;
    op[0]  = acc[0][rg] * dv;
    op[32] = acc[1][rg] * dv;
  }
}

extern "C" void kernel_launch(void* const* d_in, const int* in_sizes, int n_in,
                              void* d_out, int out_size, void* d_ws, size_t ws_size,
                              hipStream_t stream) {
  const float* x       = (const float*)d_in[0];
  const float* w       = (const float*)d_in[1];
  const float* conv_w  = (const float*)d_in[2];
  const float* dense_w = (const float*)d_in[3];
  const float* dense_b = (const float*)d_in[4];
  float* out = (float*)d_out;

  char* ws = (char*)d_ws;
  float*    sm    = (float*)ws;                        // 16 KB
  float*    sm2   = (float*)(ws + (16 << 10));         // 16 KB
  float*    dpart = (float*)(ws + (32 << 10));         // 256 KB
  _Float16* Wtf   = (_Float16*)(ws + (288 << 10));               // 4,718,592 B
  _Float16* xsp   = (_Float16*)(ws + (288 << 10) + 4718592);     // 9,469,952 B

  style_kernel<<<dim3(8, B_), 256, 0, stream>>>(w, dense_w, dense_b, sm, sm2);
  prep_kernel<<<512, 256, 0, stream>>>(conv_w, x, sm, sm2, Wtf, dpart, xsp);
  conv_kernel<<<dim3(16, 4, B_), 256, 0, stream>>>(Wtf, xsp, dpart, out);
}